// Round 2
// 291.208 us; speedup vs baseline: 1.0164x; 1.0164x over previous
//
#include <hip/hip_runtime.h>

// Problem constants
#define SEQ   2048
#define BATCH 16
#define CINCH 512
#define HDIM  512
#define NDIM  1536            // 3*H
#define TBM   (SEQ*BATCH)     // 32768 = GEMM M
#define KRED  1024            // Cin*K = GEMM K
#define NCH   32              // scan chunks
#define CHL   64              // chunk length (NCH*CHL == SEQ)
#define NCOL  8192            // B*H chains

typedef unsigned short ushort_t;
typedef __bf16 bf16x8 __attribute__((ext_vector_type(8)));
typedef unsigned short u16x8 __attribute__((ext_vector_type(8)));
typedef float f32x4 __attribute__((ext_vector_type(4)));

__device__ __forceinline__ float bf2f(ushort_t u) {
    return __uint_as_float(((unsigned int)u) << 16);
}
__device__ __forceinline__ ushort_t f2bf(float x) {
    unsigned int u = __float_as_uint(x);
    unsigned int r = u + 0x7fffu + ((u >> 16) & 1u);   // round-to-nearest-even
    return (ushort_t)(r >> 16);
}

// ---------------------------------------------------------------------------
// Kernel 1: cast x (fp32) -> bf16 with BATCH*CINCH zero prefix (concat-A trick)
// ---------------------------------------------------------------------------
__global__ void cast_x_kernel(const float* __restrict__ x, ushort_t* __restrict__ xb) {
    int i = blockIdx.x * 256 + threadIdx.x;
    int e = i * 4;
    ushort4 r;
    if (e < BATCH * CINCH) {
        r.x = 0; r.y = 0; r.z = 0; r.w = 0;
    } else {
        float4 v = *(const float4*)(x + (e - BATCH * CINCH));
        r.x = f2bf(v.x); r.y = f2bf(v.y); r.z = f2bf(v.z); r.w = f2bf(v.w);
    }
    *(ushort4*)(xb + e) = r;
}

// ---------------------------------------------------------------------------
// Kernel 2: repack W (3H, Cin, K=2) fp32 -> Wb (3H, 1024) bf16
// ---------------------------------------------------------------------------
__global__ void repack_w_kernel(const float* __restrict__ W, ushort_t* __restrict__ wb) {
    int i = blockIdx.x * 256 + threadIdx.x;
    int o  = i >> 10;
    int r  = i & 1023;
    int k  = r >> 9;
    int ci = r & 511;
    wb[i] = f2bf(W[o * 1024 + ci * 2 + k]);
}

// ---------------------------------------------------------------------------
// Kernel 3: GEMM + bias + activation.  256x256 tile, BK=64, 8 waves (2Mx4N),
// 8-phase schedule (4 phases/K-tile), counted vmcnt, setprio around MFMA,
// XOR-swizzled LDS (pre-swizzled global source for global_load_lds).
// ---------------------------------------------------------------------------
__device__ __forceinline__ void load_lds_16B(const ushort_t* g, ushort_t* l) {
    auto* gp = reinterpret_cast<const __attribute__((address_space(1))) unsigned int*>(
        reinterpret_cast<uintptr_t>(g));
    auto* lp = reinterpret_cast<__attribute__((address_space(3))) unsigned int*>(
        reinterpret_cast<uintptr_t>(l));
    __builtin_amdgcn_global_load_lds(gp, lp, 16, 0, 0);
}

__device__ __forceinline__ bf16x8 frag(const ushort_t* buf, int row, int cb) {
    // logical 8-elem block cb of row stored at phys block cb ^ (row&7)
    return __builtin_bit_cast(bf16x8,
        *(const u16x8*)(&buf[row * 64 + ((cb ^ (row & 7)) * 8)]));
}

#define PHASE_BAR() do { __builtin_amdgcn_s_barrier(); asm volatile("" ::: "memory"); } while (0)

__global__ __launch_bounds__(512, 2) void gemm_gates_kernel(
    const ushort_t* __restrict__ xb, const ushort_t* __restrict__ wb,
    const float* __restrict__ bias,
    ushort_t* __restrict__ zb, ushort_t* __restrict__ fb, ushort_t* __restrict__ ob) {

    extern __shared__ ushort_t smem[];          // 131072 B
    // layout: A0 @0, A1 @16384, B0 @32768, B1 @49152  (ushort units)

    const int tid  = threadIdx.x;
    const int w    = tid >> 6;
    const int lane = tid & 63;
    const int quad = lane >> 4;
    const int l15  = lane & 15;
    const int wm   = w >> 2;      // 0..1
    const int wn   = w & 3;       // 0..3

    // XCD-chunked bijective swizzle (768 % 8 == 0), N-tile fastest in a chunk
    const int wg    = (blockIdx.x & 7) * 96 + (blockIdx.x >> 3);
    const int mBase = (wg / 6) * 256;
    const int nBase = (wg % 6) * 256;

    // staging geometry: one call = 4 rounds x 64 rows, 16B/lane, wave-uniform dest
    const int r0    = tid >> 3;                    // 0..63
    const int cbd   = (tid & 7) ^ (r0 & 7);        // pre-swizzled source block
    const int wbase = w * 8;

    auto stageA = [&](ushort_t* dst, int u) {
        const long aoff = (u < 8) ? (long)u * 64 : 8192L + (long)(u - 8) * 64;
#pragma unroll
        for (int ra = 0; ra < 4; ++ra) {
            load_lds_16B(xb + (long)(mBase + ra * 64 + r0) * 512 + aoff + cbd * 8,
                         dst + (ra * 64 + wbase) * 64);
        }
    };
    auto stageB = [&](ushort_t* dst, int u) {
        const long koff = (long)u * 64;
#pragma unroll
        for (int ra = 0; ra < 4; ++ra) {
            load_lds_16B(wb + (long)(nBase + ra * 64 + r0) * 1024 + koff + cbd * 8,
                         dst + (ra * 64 + wbase) * 64);
        }
    };

    f32x4 acc[8][4];
#pragma unroll
    for (int i = 0; i < 8; ++i)
#pragma unroll
        for (int j = 0; j < 4; ++j)
            acc[i][j] = (f32x4){0.f, 0.f, 0.f, 0.f};

    // Prologue: tile0 fully, B(1); A(1) is staged at P1(0).
    stageA(smem, 0);
    stageB(smem + 32768, 0);
    stageB(smem + 49152, 1);
    asm volatile("s_waitcnt vmcnt(4)" ::: "memory");   // A(0),B(0) landed; B(1) in flight
    PHASE_BAR();

    int cur = 0;
    for (int t = 0; t < 16; ++t) {
        const ushort_t* cA = smem + cur * 16384;
        const ushort_t* cB = smem + 32768 + cur * 16384;
        bf16x8 a[4], b[4];

        // ---- P1: read kk0 (m0-3 + all B), stage A(t+1), MFMA acc[0..3]
#pragma unroll
        for (int mt = 0; mt < 4; ++mt) a[mt] = frag(cA, wm * 128 + mt * 16 + l15, quad);
#pragma unroll
        for (int nt = 0; nt < 4; ++nt) b[nt] = frag(cB, wn * 64 + nt * 16 + l15, quad);
        if (t < 15) stageA(smem + (cur ^ 1) * 16384, t + 1);
        __builtin_amdgcn_s_setprio(1);
#pragma unroll
        for (int mt = 0; mt < 4; ++mt)
#pragma unroll
            for (int nt = 0; nt < 4; ++nt)
                acc[mt][nt] = __builtin_amdgcn_mfma_f32_16x16x32_bf16(a[mt], b[nt], acc[mt][nt], 0, 0, 0);
        __builtin_amdgcn_s_setprio(0);
        PHASE_BAR();

        // ---- P2: read kk0 m4-7, MFMA acc[4..7]
#pragma unroll
        for (int mt = 0; mt < 4; ++mt) a[mt] = frag(cA, wm * 128 + (mt + 4) * 16 + l15, quad);
        __builtin_amdgcn_s_setprio(1);
#pragma unroll
        for (int mt = 0; mt < 4; ++mt)
#pragma unroll
            for (int nt = 0; nt < 4; ++nt)
                acc[mt + 4][nt] = __builtin_amdgcn_mfma_f32_16x16x32_bf16(a[mt], b[nt], acc[mt + 4][nt], 0, 0, 0);
        __builtin_amdgcn_s_setprio(0);
        PHASE_BAR();

        // ---- P3: read kk1 (m0-3 + all B), MFMA acc[0..3]
#pragma unroll
        for (int mt = 0; mt < 4; ++mt) a[mt] = frag(cA, wm * 128 + mt * 16 + l15, 4 + quad);
#pragma unroll
        for (int nt = 0; nt < 4; ++nt) b[nt] = frag(cB, wn * 64 + nt * 16 + l15, 4 + quad);
        __builtin_amdgcn_s_setprio(1);
#pragma unroll
        for (int mt = 0; mt < 4; ++mt)
#pragma unroll
            for (int nt = 0; nt < 4; ++nt)
                acc[mt][nt] = __builtin_amdgcn_mfma_f32_16x16x32_bf16(a[mt], b[nt], acc[mt][nt], 0, 0, 0);
        __builtin_amdgcn_s_setprio(0);
        PHASE_BAR();

        // ---- P4: read kk1 m4-7, MFMA acc[4..7], stage B(t+2), counted vmcnt
#pragma unroll
        for (int mt = 0; mt < 4; ++mt) a[mt] = frag(cA, wm * 128 + (mt + 4) * 16 + l15, 4 + quad);
        __builtin_amdgcn_s_setprio(1);
#pragma unroll
        for (int mt = 0; mt < 4; ++mt)
#pragma unroll
            for (int nt = 0; nt < 4; ++nt)
                acc[mt + 4][nt] = __builtin_amdgcn_mfma_f32_16x16x32_bf16(a[mt], b[nt], acc[mt + 4][nt], 0, 0, 0);
        __builtin_amdgcn_s_setprio(0);
        if (t < 14) {
            stageB(smem + 32768 + cur * 16384, t + 2);      // region free since P3
            asm volatile("s_waitcnt vmcnt(4)" ::: "memory"); // A(t+1),B(t+1) landed
        } else {
            asm volatile("s_waitcnt vmcnt(0)" ::: "memory"); // drain tail (A(15))
        }
        PHASE_BAR();
        cur ^= 1;
    }

    // ---- Epilogue: bias + activation -> LDS (256x256 bf16, swizzled) -> stores
    const int gate = nBase >> 9;            // block-uniform (256-tile within a gate)
    const int hb   = nBase & 511;

#pragma unroll
    for (int nt = 0; nt < 4; ++nt) {
        const int n_local = wn * 64 + nt * 16 + l15;
        const float bv = bias[nBase + n_local];
#pragma unroll
        for (int mt = 0; mt < 8; ++mt) {
#pragma unroll
            for (int r = 0; r < 4; ++r) {
                const int m_local = wm * 128 + mt * 16 + quad * 4 + r;
                float g = acc[mt][nt][r] + bv;
                float av;
                if (gate == 0) {
                    float e = __expf(-2.f * fabsf(g));
                    float tt = (1.f - e) / (1.f + e);
                    av = copysignf(tt, g);
                } else {
                    av = 1.f / (1.f + __expf(-g));
                }
                const int phys = ((n_local >> 3) ^ (m_local & 7)) * 8 + (n_local & 7);
                smem[m_local * 256 + phys] = f2bf(av);
            }
        }
    }
    __syncthreads();

    ushort_t* outp = (gate == 0) ? zb : (gate == 1) ? fb : ob;
    const int lb    = tid & 31;
    const int mrow0 = tid >> 5;
#pragma unroll
    for (int s = 0; s < 16; ++s) {
        const int m_local = s * 16 + mrow0;
        u16x8 v = *(const u16x8*)(&smem[m_local * 256 + ((lb ^ (m_local & 7)) * 8)]);
        *(u16x8*)(outp + (long)(mBase + m_local) * 512 + hb + lb * 8) = v;
    }
}

// ---------------------------------------------------------------------------
// Scan, chunked-parallel (3 passes), vec4 columns (8B bf16 loads, 16B stores).
// ---------------------------------------------------------------------------
__device__ __forceinline__ void scan_step(float z, float f, float& A, float& Bv) {
    Bv = f * Bv + (1.f - f) * z;
    A *= f;
}

__global__ __launch_bounds__(256) void scan_compose(
    const ushort_t* __restrict__ zb, const ushort_t* __restrict__ fb,
    float* __restrict__ Acomp, float* __restrict__ Bcomp) {
    const int cg  = (blockIdx.x & 7) * 256 + threadIdx.x;   // 2048 col-groups/chunk
    const int ch  = blockIdx.x >> 3;
    const int col = cg * 4;
    const long base = (long)ch * CHL * NCOL + col;
    float Ax = 1.f, Ay = 1.f, Az = 1.f, Aw = 1.f;
    float Bx = 0.f, By = 0.f, Bz = 0.f, Bw = 0.f;
    const int U = 8;
    for (int w0 = 0; w0 < CHL; w0 += U) {
        ushort4 zr[U], fr[U];
#pragma unroll
        for (int u = 0; u < U; ++u) {
            const long idx = base + (long)(w0 + u) * NCOL;
            zr[u] = *(const ushort4*)(zb + idx);
            fr[u] = *(const ushort4*)(fb + idx);
        }
#pragma unroll
        for (int u = 0; u < U; ++u) {
            scan_step(bf2f(zr[u].x), bf2f(fr[u].x), Ax, Bx);
            scan_step(bf2f(zr[u].y), bf2f(fr[u].y), Ay, By);
            scan_step(bf2f(zr[u].z), bf2f(fr[u].z), Az, Bz);
            scan_step(bf2f(zr[u].w), bf2f(fr[u].w), Aw, Bw);
        }
    }
    *(float4*)(Acomp + (long)ch * NCOL + col) = make_float4(Ax, Ay, Az, Aw);
    *(float4*)(Bcomp + (long)ch * NCOL + col) = make_float4(Bx, By, Bz, Bw);
}

__global__ void scan_prefix(const float* __restrict__ Acomp,
                            const float* __restrict__ Bcomp,
                            float* __restrict__ Cin) {
    const int col = blockIdx.x * 256 + threadIdx.x;
    float c = 0.f;
#pragma unroll 4
    for (int ch = 0; ch < NCH; ++ch) {
        Cin[ch * NCOL + col] = c;
        c = Acomp[ch * NCOL + col] * c + Bcomp[ch * NCOL + col];
    }
}

__global__ __launch_bounds__(256) void scan_apply(
    const ushort_t* __restrict__ zb, const ushort_t* __restrict__ fb,
    const ushort_t* __restrict__ ob, const float* __restrict__ Cin,
    float* __restrict__ out) {
    const int cg  = (blockIdx.x & 7) * 256 + threadIdx.x;
    const int ch  = blockIdx.x >> 3;
    const int col = cg * 4;
    const long base = (long)ch * CHL * NCOL + col;
    float4 c0 = *(const float4*)(Cin + (long)ch * NCOL + col);
    float cx = c0.x, cy = c0.y, cz = c0.z, cw = c0.w;
    float hx = 0.f, hy = 0.f, hz = 0.f, hw = 0.f;
    const int U = 8;
    for (int w0 = 0; w0 < CHL; w0 += U) {
        ushort4 zr[U], fr[U], orr[U];
#pragma unroll
        for (int u = 0; u < U; ++u) {
            const long idx = base + (long)(w0 + u) * NCOL;
            zr[u]  = *(const ushort4*)(zb + idx);
            fr[u]  = *(const ushort4*)(fb + idx);
            orr[u] = *(const ushort4*)(ob + idx);
        }
#pragma unroll
        for (int u = 0; u < U; ++u) {
            float f, z;
            f = bf2f(fr[u].x); z = bf2f(zr[u].x); cx = f * cx + (1.f - f) * z; hx = cx * bf2f(orr[u].x);
            f = bf2f(fr[u].y); z = bf2f(zr[u].y); cy = f * cy + (1.f - f) * z; hy = cy * bf2f(orr[u].y);
            f = bf2f(fr[u].z); z = bf2f(zr[u].z); cz = f * cz + (1.f - f) * z; hz = cz * bf2f(orr[u].z);
            f = bf2f(fr[u].w); z = bf2f(zr[u].w); cw = f * cw + (1.f - f) * z; hw = cw * bf2f(orr[u].w);
            *(float4*)(out + base + (long)(w0 + u) * NCOL) = make_float4(hx, hy, hz, hw);
        }
    }
    if (ch == NCH - 1) {
        *(float4*)(out + (long)SEQ * NCOL + col)        = make_float4(hx, hy, hz, hw);  // h_last
        *(float4*)(out + (long)SEQ * NCOL + NCOL + col) = make_float4(cx, cy, cz, cw);  // c_last
    }
}

// ---------------------------------------------------------------------------
extern "C" void kernel_launch(void* const* d_in, const int* in_sizes, int n_in,
                              void* d_out, int out_size, void* d_ws, size_t ws_size,
                              hipStream_t stream) {
    const float* x  = (const float*)d_in[0];   // (T, B, Cin)
    const float* W  = (const float*)d_in[1];   // (3H, Cin, 2)
    const float* bi = (const float*)d_in[2];   // (3H,)
    float* out = (float*)d_out;

    char* ws = (char*)d_ws;
    const size_t xbN = (size_t)(TBM + BATCH) * CINCH;   // padded bf16 x
    const size_t wbN = (size_t)NDIM * KRED;
    const size_t gN  = (size_t)TBM * HDIM;
    ushort_t* xb = (ushort_t*)ws;
    ushort_t* wb = (ushort_t*)(ws + xbN * 2);
    ushort_t* zb = (ushort_t*)(ws + xbN * 2 + wbN * 2);
    ushort_t* fb = zb + gN;
    ushort_t* ob = fb + gN;
    // scan scratch reuses the xb region (dead after the GEMM)
    float* Acomp = (float*)ws;
    float* Bcomp = Acomp + NCH * NCOL;
    float* Cin   = Bcomp + NCH * NCOL;

    static bool s_attr_set = false;
    if (!s_attr_set) {
        (void)hipFuncSetAttribute(reinterpret_cast<const void*>(&gemm_gates_kernel),
                                  hipFuncAttributeMaxDynamicSharedMemorySize, 131072);
        s_attr_set = true;
    }

    cast_x_kernel<<<16392, 256, 0, stream>>>(x, xb);
    repack_w_kernel<<<6144, 256, 0, stream>>>(W, wb);
    gemm_gates_kernel<<<dim3(768), 512, 131072, stream>>>(xb, wb, bi, zb, fb, ob);
    scan_compose<<<NCH * 8, 256, 0, stream>>>(zb, fb, Acomp, Bcomp);
    scan_prefix<<<NCOL / 256, 256, 0, stream>>>(Acomp, Bcomp, Cin);
    scan_apply<<<NCH * 8, 256, 0, stream>>>(zb, fb, ob, Cin, out);
}